// Round 1
// baseline (336.952 us; speedup 1.0000x reference)
//
#include <hip/hip_runtime.h>

#define NB    3
#define SKIPC 85
#define CCH   255        // NB * SKIPC
#define WW    76
#define HWSZ  5776       // 76*76
#define THW   16         // hw positions per block tile (5776 = 361*16)
#define LSTRIDE 17       // THW + 1 pad -> odd stride, conflict-free LDS column reads

// anchors / 608, interleaved (aw0,ah0,aw1,ah1,aw2,ah2)
__device__ __constant__ float c_awh[6] = {
    116.0f/608.0f, 90.0f/608.0f,
    156.0f/608.0f, 198.0f/608.0f,
    373.0f/608.0f, 326.0f/608.0f
};

__global__ __launch_bounds__(256) void yolo_decode_kernel(
    const float* __restrict__ x, float* __restrict__ out)
{
    __shared__ float lds[CCH * LSTRIDE];
    const int b   = blockIdx.y;
    const int hw0 = blockIdx.x * THW;
    const int t   = threadIdx.x;

    // ---- Load 255 channels x 16 hw positions into LDS (float4, coalesced).
    // Each input row segment is one aligned 64B cache line.
    const float* xin = x + (size_t)b * CCH * HWSZ + hw0;
    for (int i = t; i < CCH * (THW / 4); i += 256) {
        const int ch = i >> 2;
        const int c4 = (i & 3) << 2;
        const float4 v = *(const float4*)(xin + (size_t)ch * HWSZ + c4);
        float* d = &lds[ch * LSTRIDE + c4];
        d[0] = v.x; d[1] = v.y; d[2] = v.z; d[3] = v.w;
    }
    __syncthreads();

    // ---- Transform + write. Output chunk for this block is fully contiguous:
    // out[(b*HWSZ + hw0)*255 ... +16*255). Element o -> hwl = o/255, cc = o%255.
    float* op = out + ((size_t)b * HWSZ + hw0) * CCH;
    const float inv76 = 1.0f / 76.0f;

    for (int o = t; o < CCH * THW; o += 256) {
        const int hwl = o / CCH;
        const int cc  = o - hwl * CCH;          // nb*85 + c
        const int nb  = cc / SKIPC;
        const int c   = cc - nb * SKIPC;
        const float v = lds[cc * LSTRIDE + hwl];

        const bool is_wh = (c == 2) | (c == 3);
        // one transcendental per element: exp(v) for wh, exp(-v) for sigmoid
        const float ev  = __expf(is_wh ? v : -v);
        const float sig = 1.0f / (1.0f + ev);

        float r;
        if (is_wh) {
            r = c_awh[(nb << 1) + (c - 2)] * ev;
        } else if (c == 0) {
            const int w = (hw0 + hwl) % WW;
            r = (sig + (float)w) * inv76;
        } else if (c == 1) {
            const int h = (hw0 + hwl) / WW;
            r = (sig + (float)h) * inv76;
        } else {
            r = sig;                             // objectness + classes
        }
        op[o] = r;
    }
}

extern "C" void kernel_launch(void* const* d_in, const int* in_sizes, int n_in,
                              void* d_out, int out_size, void* d_ws, size_t ws_size,
                              hipStream_t stream) {
    const float* x = (const float*)d_in[0];
    float* out = (float*)d_out;
    const int B = in_sizes[0] / (CCH * HWSZ);   // = 32
    dim3 grid(HWSZ / THW, B);                   // (361, 32)
    yolo_decode_kernel<<<grid, 256, 0, stream>>>(x, out);
}

// Round 2
// 314.147 us; speedup vs baseline: 1.0726x; 1.0726x over previous
//
#include <hip/hip_runtime.h>

#define CCH   255        // NB * SKIPC
#define SKIPC 85
#define WW    76
#define HWSZ  5776       // 76*76
#define THW   16         // hw positions per block tile (5776 = 361*16)
#define TILE  (CCH*THW)  // 4080 elements per block

// Phase A: coalesced float4 loads along hw; transform immediately (channel is
// known per lane -> meta computed once per float4, rare channels behind
// wave-coherent branches); write results to LDS in flat output order.
// Phase B: pure LDS b128 -> global dwordx4 copy (output chunk is contiguous).
__global__ __launch_bounds__(256) void yolo_decode_kernel(
    const float* __restrict__ x, float* __restrict__ out)
{
    __shared__ float lds[TILE];            // results, flat [hwl*255 + cc]
    const int b   = blockIdx.y;
    const int hw0 = blockIdx.x * THW;
    const int t   = threadIdx.x;

    const int sw = hw0 % WW;               // block-uniform grid col/row base
    const int sh = hw0 / WW;

    const float* xin = x + (size_t)b * ((size_t)CCH * HWSZ) + hw0;
    const float inv76 = 1.0f / (float)WW;

    #pragma unroll
    for (int k = 0; k < 4; ++k) {
        const int i = t + 256 * k;         // float4 index over the tile
        if (i < TILE / 4) {
            const int ch = i >> 2;         // 0..254
            const int c4 = (i & 3) << 2;   // hw sub-offset: 0,4,8,12
            const float4 v4 = *(const float4*)(xin + (size_t)ch * HWSZ + c4);

            // channel meta, once per float4:  nb = ch/85 (exact for ch<255)
            const int nb = (ch * 193) >> 14;
            const int c  = ch - nb * SKIPC;

            float a = 0.0f, bs = 1.0f, sgn = -1.0f;
            if ((unsigned)(c - 2) < 2u) {  // c==2 || c==3  (w/h channels)
                bs = 0.0f; sgn = 1.0f;
                const float aw = (nb == 0) ? 0.19078947f : ((nb == 1) ? 0.25657895f : 0.61348684f);
                const float ah = (nb == 0) ? 0.14802632f : ((nb == 1) ? 0.32565789f : 0.53618421f);
                a = (c == 2) ? aw : ah;
            }
            const bool fw = (c == 0);
            const bool fh = (c == 1);
            if (c < 2) bs = inv76;

            const float vv[4] = {v4.x, v4.y, v4.z, v4.w};
            float* dst = &lds[c4 * CCH + ch];
            #pragma unroll
            for (int e = 0; e < 4; ++e) {
                const float ev  = __expf(sgn * vv[e]);                  // v_mul + v_exp
                const float sig = __builtin_amdgcn_rcpf(1.0f + ev);     // v_add + v_rcp
                float g = 0.0f;
                if (fw | fh) {             // wave-coherent: skipped for 243/255 channels
                    const int hwl = c4 + e;
                    const int w  = sw + hwl;
                    const int wr = (w >= WW) ? (w - WW) : w;
                    const int hr = sh + ((w >= WW) ? 1 : 0);
                    g = fw ? (float)wr : (float)hr;
                }
                dst[e * CCH] = fmaf(a, ev, bs * (sig + g));
            }
        }
    }

    __syncthreads();

    // Phase B: contiguous copy-out, 16B per lane both sides.
    float* op = out + ((size_t)b * HWSZ + hw0) * (size_t)CCH;
    #pragma unroll
    for (int k = 0; k < 4; ++k) {
        const int i = t + 256 * k;
        if (i < TILE / 4) {
            const float4 v = *(const float4*)&lds[i << 2];
            *(float4*)(op + ((size_t)i << 2)) = v;
        }
    }
}

extern "C" void kernel_launch(void* const* d_in, const int* in_sizes, int n_in,
                              void* d_out, int out_size, void* d_ws, size_t ws_size,
                              hipStream_t stream) {
    const float* x = (const float*)d_in[0];
    float* out = (float*)d_out;
    const int B = in_sizes[0] / (CCH * HWSZ);   // 32
    dim3 grid(HWSZ / THW, B);                   // (361, 32)
    yolo_decode_kernel<<<grid, 256, 0, stream>>>(x, out);
}